// Round 17
// baseline (257.069 us; speedup 1.0000x reference)
//
#include <hip/hip_runtime.h>
#include <math.h>

#define NB   16
#define NBEF 512
#define NSTK 256
#define CCO  128
#define SPIN 512
#define SPOUT 256
#define DNIN 128
#define DNOUT 128
#define NPNT 32
#define SP_ELEMS (NB * SPOUT * NBEF)   // 2,097,152 f32 elems (sparse output)
#define XT_COLS 16416                  // 16386 used + pad to 16416

typedef __attribute__((ext_vector_type(8))) short bf16x8v;   // 8 bf16 = 4 VGPR
typedef __attribute__((ext_vector_type(4))) float f32x4v;    // MFMA C/D

typedef __attribute__((address_space(1))) const unsigned int* gas1_t;
typedef __attribute__((address_space(3))) unsigned int* las3_t;

__device__ __forceinline__ unsigned short f32_to_bf16(float f) {
    unsigned int u = __float_as_uint(f);
    u += 0x7fffu + ((u >> 16) & 1u);     // round-to-nearest-even
    return (unsigned short)(u >> 16);
}

// gelu(tanh approx) with hw exp2: tanh(z)=sign(z)*(1-2/(2^(2|z|*log2e)+1))
__device__ __forceinline__ float fast_gelu(float x) {
    float z = 0.7978845608028654f * x * (1.0f + 0.044715f * x * x);
    float az = fabsf(z) * 2.885390081777927f;   // 2*log2(e)
    float e;
    asm("v_exp_f32 %0, %1" : "=v"(e) : "v"(az));
    float r = __builtin_amdgcn_rcpf(e + 1.0f);
    float th = copysignf(1.0f - 2.0f * r, z);
    return 0.5f * x * (1.0f + th);
}

// order-preserving float -> uint map
__device__ __forceinline__ unsigned int f2ord(float f) {
    unsigned int u = __float_as_uint(f);
    return (u & 0x80000000u) ? ~u : (u | 0x80000000u);
}
__device__ __forceinline__ float ord2f(unsigned int o) {
    unsigned int u = (o & 0x80000000u) ? (o & 0x7fffffffu) : ~o;
    return __uint_as_float(u);
}

__device__ __forceinline__ unsigned long long wave_min_u64(unsigned long long k) {
    #pragma unroll
    for (int d = 32; d >= 1; d >>= 1) {
        unsigned long long o = __shfl_xor(k, d, 64);
        if (o < k) k = o;
    }
    return k;
}

// ---------------- Kernel 0: tiled 2-NN (v2 — measured best) ----------------
__global__ __launch_bounds__(256) void knn_kernel(
    const float* __restrict__ stk_coor,      // [B][256][128]
    const float* __restrict__ stk_coor_bef,  // [B][512][128]
    int2* __restrict__ idx_out,              // [B][512]
    float2* __restrict__ w_out)              // [B][512]
{
    int b  = blockIdx.y;
    int q0 = blockIdx.x * 16;
    int tid  = threadIdx.x;
    int lane = tid & 63;
    int qg   = tid >> 6;                     // wave id: queries qg*4..+4
    int pg   = lane;                         // points pg*4..+4

    __shared__ float Qt[128][16];            // [c][q] 8 KB
    __shared__ float Pt[32][260];            // [c-chunk][p] 33.3 KB (pad 4)

    {
        int q = tid >> 4, c0 = (tid & 15) * 8;
        const float* src = stk_coor_bef + ((size_t)b * NBEF + q0 + q) * CCO + c0;
        float4 v0 = *reinterpret_cast<const float4*>(src);
        float4 v1 = *reinterpret_cast<const float4*>(src + 4);
        Qt[c0+0][q] = v0.x; Qt[c0+1][q] = v0.y; Qt[c0+2][q] = v0.z; Qt[c0+3][q] = v0.w;
        Qt[c0+4][q] = v1.x; Qt[c0+5][q] = v1.y; Qt[c0+6][q] = v1.z; Qt[c0+7][q] = v1.w;
    }

    float dot[4][4];
    #pragma unroll
    for (int a = 0; a < 4; ++a)
        #pragma unroll
        for (int c = 0; c < 4; ++c) dot[a][c] = 0.f;
    float qn[4] = {0.f, 0.f, 0.f, 0.f};
    float pn[4] = {0.f, 0.f, 0.f, 0.f};

    for (int ct = 0; ct < 4; ++ct) {
        __syncthreads();
        #pragma unroll
        for (int it = 0; it < 8; ++it) {
            int p  = (tid >> 3) + it * 32;
            int cl = (tid & 7) * 4;
            float4 v = *reinterpret_cast<const float4*>(
                stk_coor + ((size_t)b * NSTK + p) * CCO + ct * 32 + cl);
            Pt[cl+0][p] = v.x; Pt[cl+1][p] = v.y; Pt[cl+2][p] = v.z; Pt[cl+3][p] = v.w;
        }
        __syncthreads();
        #pragma unroll 8
        for (int c = 0; c < 32; ++c) {
            float4 qv = *reinterpret_cast<const float4*>(&Qt[ct*32 + c][qg*4]);
            float4 pv = *reinterpret_cast<const float4*>(&Pt[c][pg*4]);
            float qa[4] = {qv.x, qv.y, qv.z, qv.w};
            float pa[4] = {pv.x, pv.y, pv.z, pv.w};
            #pragma unroll
            for (int j = 0; j < 4; ++j) {
                qn[j] += qa[j] * qa[j];
                pn[j] += pa[j] * pa[j];
                #pragma unroll
                for (int k = 0; k < 4; ++k) dot[j][k] += qa[j] * pa[k];
            }
        }
    }

    #pragma unroll
    for (int qj = 0; qj < 4; ++qj) {
        unsigned long long kA = 0xFFFFFFFFFFFFFFFFull, kB = 0xFFFFFFFFFFFFFFFFull;
        #pragma unroll
        for (int pj = 0; pj < 4; ++pj) {
            float d2 = qn[qj] + pn[pj] - 2.f * dot[qj][pj];
            unsigned long long key =
                ((unsigned long long)f2ord(d2) << 32) | (unsigned int)(pg * 4 + pj);
            if (key < kA)      { kB = kA; kA = key; }
            else if (key < kB) { kB = key; }
        }
        unsigned long long m0 = wave_min_u64(kA);
        unsigned long long c2 = (kA == m0) ? kB : kA;
        unsigned long long m1 = wave_min_u64(c2);
        if (lane == 0) {
            float d0 = ord2f((unsigned int)(m0 >> 32));
            float d1 = ord2f((unsigned int)(m1 >> 32));
            int j0 = (int)(m0 & 0xffffffffu), j1 = (int)(m1 & 0xffffffffu);
            float r0 = 1.f / (d0 + 1e-8f);
            float r1 = 1.f / (d1 + 1e-8f);
            float s = r0 + r1;
            int q = q0 + qg * 4 + qj;
            idx_out[b * NBEF + q] = make_int2(j0, j1);
            w_out[b * NBEF + q]   = make_float2(r0 / s, r1 / s);
        }
    }
}

// ---------------- Kernel 1: one-time A-matrix -> MFMA-fragment-linear bf16 ----------------
__global__ __launch_bounds__(256) void prep_a_kernel(
    const float* __restrict__ w_ct,          // [128][128][4]
    unsigned short* __restrict__ Aws)        // 65536 bf16
{
    int g = blockIdx.x * 256 + threadIdx.x;  // 0..8191
    int lane = g & 63;
    int ks = (g >> 6) & 7;
    int mt16 = g >> 9;
    int m = mt16 * 16 + (lane & 15);
    int o = m & 127;
    int modd = (m >= 128);
    unsigned short t8[8];
    #pragma unroll
    for (int j = 0; j < 8; ++j) {
        int k = ks * 32 + (lane >> 4) * 8 + j;
        int i = k & 127;
        int tap = modd ? (k < 128 ? 2 : 0) : (k < 128 ? 3 : 1);
        t8[j] = f32_to_bf16(w_ct[((size_t)i * DNOUT + o) * 4 + tap]);
    }
    *reinterpret_cast<uint4*>(Aws + (size_t)g * 8) = *reinterpret_cast<const uint4*>(t8);
}

// ---------------- Kernel 2: one-time w_sp quad-transpose -> wTq[c4][o] float4 ----------------
__global__ __launch_bounds__(256) void prep_wt_kernel(
    const float* __restrict__ w_sp,          // [256][512]
    float4* __restrict__ wTq)                // [128][256]
{
    int c4 = blockIdx.x;                     // 0..127
    int o  = threadIdx.x;                    // 0..255
    float4 v = *reinterpret_cast<const float4*>(w_sp + (size_t)o * SPIN + c4 * 4);
    wTq[c4 * 256 + o] = v;
}

// ---------------- Kernel 3: stage XT — gather+interp per stroke -> global bf16 ----------------
// XT[b][u][i] bf16, u in [0, 16416): XT[u] col = x[clamp(u-1, 0, 16383)], per-col swizzled
// chunk layout: elem (u, i) at u*128 + ((i>>3 ^ (u&15))<<3) + (i&7).  Stroke t writes
// u = 32t+1+sp; t=0 also u=0 (==x[0]); t=511 also u=16385 (==x[16383]) + zero pad 16386..16415.
__global__ __launch_bounds__(256) void stage_xt_kernel(
    const float* __restrict__ DF,            // [16][128][256][32]
    const int2* __restrict__ idxws, const float2* __restrict__ wgtws,
    unsigned short* __restrict__ XT)         // [16][16416][128]
{
    int t = blockIdx.x;                      // stroke 0..511
    int b = blockIdx.y;
    int tid = threadIdx.x;
    int sp = tid & 31, ig = tid >> 5;        // ig 0..7
    int2  ij = idxws[b * NBEF + t];
    float2 w = wgtws[b * NBEF + t];
    const float* DFb = DF + (size_t)b * (DNIN * NSTK * NPNT);
    const float* r0 = DFb + (size_t)ij.x * NPNT + sp;
    const float* r1 = DFb + (size_t)ij.y * NPNT + sp;
    unsigned short* XTb = XT + (size_t)b * XT_COLS * 128;

    unsigned short t8a[8], t8b[8];
    #pragma unroll
    for (int p = 0; p < 16; ++p) {
        int i = ig * 16 + p;                 // chunks 2ig (p<8), 2ig+1 (p>=8)
        float v = w.x * r0[(size_t)i * 8192] + w.y * r1[(size_t)i * 8192];
        if (p < 8) t8a[p] = f32_to_bf16(v); else t8b[p - 8] = f32_to_bf16(v);
    }
    int u = 32 * t + 1 + sp;
    int c0 = 2 * ig, c1 = 2 * ig + 1;
    *reinterpret_cast<uint4*>(&XTb[(size_t)u * 128 + ((c0 ^ (u & 15)) << 3)]) =
        *reinterpret_cast<const uint4*>(t8a);
    *reinterpret_cast<uint4*>(&XTb[(size_t)u * 128 + ((c1 ^ (u & 15)) << 3)]) =
        *reinterpret_cast<const uint4*>(t8b);

    if (t == 0 && sp == 0) {                 // u=0: x[clamp(-1)]=x[0] == this thread's values
        *reinterpret_cast<uint4*>(&XTb[(c0 ^ 0) << 3]) = *reinterpret_cast<const uint4*>(t8a);
        *reinterpret_cast<uint4*>(&XTb[(c1 ^ 0) << 3]) = *reinterpret_cast<const uint4*>(t8b);
    }
    if (t == NBEF - 1) {
        if (sp == 31) {                      // u=16385: x[clamp(16384)]=x[16383] == this thread's
            int uu = 16385;
            *reinterpret_cast<uint4*>(&XTb[(size_t)uu * 128 + ((c0 ^ (uu & 15)) << 3)]) =
                *reinterpret_cast<const uint4*>(t8a);
            *reinterpret_cast<uint4*>(&XTb[(size_t)uu * 128 + ((c1 ^ (uu & 15)) << 3)]) =
                *reinterpret_cast<const uint4*>(t8b);
        }
        if (tid < 16) {                      // zero pad cols 16386..16415
            uint4 z = make_uint4(0, 0, 0, 0);
            for (int uu = 16386; uu < XT_COLS; ++uu)
                *reinterpret_cast<uint4*>(&XTb[(size_t)uu * 128 + tid * 8]) = z;
        }
    }
}

// ---------------- Kernel A: fused sparse branch (R12 version — measured best) ----------------
__global__ __launch_bounds__(256) void sparse_direct_kernel(
    const float* __restrict__ SF,            // [16][512][256]
    const float* __restrict__ w_sp,          // [256][512] (fallback path)
    const float4* __restrict__ wTq,          // [128][256] transposed weights (or null)
    const int2* __restrict__ idxws, const float2* __restrict__ wgtws,
    const float* __restrict__ b_sp, const float* __restrict__ gamma_sp,
    const float* __restrict__ beta_sp,
    float* __restrict__ out)                 // [16][256][512] f32
{
    int b = blockIdx.y;
    int n0 = blockIdx.x * 8;                 // grid.x = 64
    int tid = threadIdx.x;

    __shared__ float fs[SPIN][8];            // 16 KB
    __shared__ int2   sij[8];
    __shared__ float2 swt[8];

    if (tid < 8) {
        sij[tid] = idxws[b * NBEF + n0 + tid];
        swt[tid] = wgtws[b * NBEF + n0 + tid];
    }
    __syncthreads();

    for (int l = tid; l < SPIN * 8; l += 256) {
        int c = l >> 3, nn = l & 7;
        int2  ij = sij[nn];
        float2 w = swt[nn];
        const float* row = SF + ((size_t)b * SPIN + c) * NSTK;
        fs[c][nn] = w.x * row[ij.x] + w.y * row[ij.y];
    }
    __syncthreads();

    int o = tid;
    float acc[8] = {0,0,0,0,0,0,0,0};
    if (wTq) {
        #pragma unroll 4
        for (int c4 = 0; c4 < SPIN / 4; ++c4) {
            float4 a = wTq[c4 * 256 + o];
            int c = c4 * 4;
            #pragma unroll
            for (int nn = 0; nn < 8; ++nn)
                acc[nn] += a.x * fs[c][nn] + a.y * fs[c+1][nn]
                         + a.z * fs[c+2][nn] + a.w * fs[c+3][nn];
        }
    } else {
        const float4* wr4 = reinterpret_cast<const float4*>(w_sp + (size_t)o * SPIN);
        #pragma unroll 4
        for (int c4 = 0; c4 < SPIN / 4; ++c4) {
            float4 a = wr4[c4];
            int c = c4 * 4;
            #pragma unroll
            for (int nn = 0; nn < 8; ++nn)
                acc[nn] += a.x * fs[c][nn] + a.y * fs[c+1][nn]
                         + a.z * fs[c+2][nn] + a.w * fs[c+3][nn];
        }
    }

    const float invs = 1.0f / sqrtf(1.0f + 1e-5f);
    float bias  = b_sp[o];
    float scale = gamma_sp[o] * invs;
    float beta  = beta_sp[o];
    float r[8];
    #pragma unroll
    for (int q = 0; q < 8; ++q)
        r[q] = fast_gelu((acc[q] + bias) * scale + beta);
    float* dst = out + ((size_t)b * SPOUT + o) * NBEF + n0;
    *reinterpret_cast<float4*>(dst)     = make_float4(r[0], r[1], r[2], r[3]);
    *reinterpret_cast<float4*>(dst + 4) = make_float4(r[4], r[5], r[6], r[7]);
}

// ---------------- Kernel B2: dense MFMA from pre-staged XT (trivial contiguous staging) -------
// LDS Xs = verbatim copy of XT cols [128*blk, 128*blk+146) (37376 B, already swizzled with
// key u&15 == local c&15 since 128*blk ≡ 0 mod 16).  Then MFMA + epilogue identical to R16.
__global__ __launch_bounds__(512, 4) void dense_mfma2_kernel(
    const unsigned short* __restrict__ XT,   // [16][16416][128] bf16
    const unsigned short* __restrict__ Aws,  // fragment-linear A, 128 KB
    const float* __restrict__ b_ct,
    const float* __restrict__ gamma_dn,
    const float* __restrict__ beta_dn,
    float* __restrict__ outd)                // [16][128][32768] f32 (already offset)
{
    int blk = blockIdx.x;                    // 0..127
    int b   = blockIdx.y;
    int T0  = blk * 256;
    int tid  = threadIdx.x;
    int lane = tid & 63;
    int wid  = tid >> 6;
    int rit  = lane & 15;
    int kgrp = lane >> 4;

    __shared__ unsigned short Xs[146 * 128]; // 37376 B
    __shared__ float bnb[128], bns[128], bnt[128];

    const float invs = 1.0f / sqrtf(1.0f + 1e-5f);
    if (tid < 128) {
        bnb[tid] = b_ct[tid];
        bns[tid] = gamma_dn[tid] * invs;
        bnt[tid] = beta_dn[tid];
    }

    // contiguous DMA copy: 37376 B in 5 rounds of tid*16 + r*8192
    const char* src = (const char*)(XT + ((size_t)b * XT_COLS + (size_t)blk * 128) * 128);
    #pragma unroll
    for (int r = 0; r < 5; ++r) {
        int off = tid * 16 + r * 8192;
        if (off < 37376) {
            __builtin_amdgcn_global_load_lds((gas1_t)(const void*)(src + off),
                (las3_t)(void*)((char*)Xs + off), 16, 0, 0);
        }
    }

    // A fragments: coalesced 16B loads from fragment-linear ws
    bf16x8v afrag[2][8];
    #pragma unroll
    for (int mt = 0; mt < 2; ++mt) {
        int mt16 = wid + mt * 8;
        #pragma unroll
        for (int ks = 0; ks < 8; ++ks) {
            afrag[mt][ks] = *reinterpret_cast<const bf16x8v*>(
                Aws + (((size_t)(mt16 * 8 + ks)) * 64 + lane) * 8);
        }
    }
    __syncthreads();                         // DMA + bn ready

    // MFMA: ks-outer / nt-inner, acc[9][2] resident
    f32x4v acc[9][2];
    #pragma unroll
    for (int nt = 0; nt < 9; ++nt) {
        acc[nt][0] = (f32x4v){0.f, 0.f, 0.f, 0.f};
        acc[nt][1] = (f32x4v){0.f, 0.f, 0.f, 0.f};
    }
    #pragma unroll
    for (int ks = 0; ks < 8; ++ks) {
        int kb   = ks * 32 + kgrp * 8;
        int half = kb >> 7;
        int i    = kb & 127;
        #pragma unroll
        for (int nt = 0; nt < 9; ++nt) {
            int col = nt * 16 + rit + half;
            int srcx = col * 128 + ((((i >> 3) ^ (col & 15))) << 3);
            bf16x8v bfrag = *reinterpret_cast<const bf16x8v*>(&Xs[srcx]);
            acc[nt][0] = __builtin_amdgcn_mfma_f32_16x16x32_bf16(afrag[0][ks], bfrag, acc[nt][0], 0, 0, 0);
            acc[nt][1] = __builtin_amdgcn_mfma_f32_16x16x32_bf16(afrag[1][ks], bfrag, acc[nt][1], 0, 0, 0);
        }
    }

    // epilogue (identical math to R16)
    int srcl = (lane & 48) | ((lane + 1) & 15);
    #pragma unroll
    for (int nt = 0; nt < 9; ++nt) {
        int c = nt * 16 + rit;
        #pragma unroll
        for (int q = 0; q < 4; ++q) {
            float a1n = __shfl(acc[nt][1][q], srcl, 64);
            int o = wid * 16 + kgrp * 4 + q;
            float bias = bnb[o], scale = bns[o], beta = bnt[o];
            size_t rowbase = (((size_t)b * DNOUT + o) << 15) + (size_t)T0;
            if (c < 128) {
                float ye = fast_gelu((acc[nt][0][q] + bias) * scale + beta);
                if (rit < 15) {
                    float yo = fast_gelu((a1n + bias) * scale + beta);
                    *reinterpret_cast<float2*>(outd + rowbase + 2 * c) = make_float2(ye, yo);
                } else {
                    outd[rowbase + 2 * c] = ye;
                }
            }
            if (rit == 0 && c >= 1) {
                float yo0 = fast_gelu((acc[nt][1][q] + bias) * scale + beta);
                outd[rowbase + 2 * c - 1] = yo0;
            }
        }
    }
}

// ---------------- Kernel B (fallback): R16 dense, used only if ws too small ----------------
__global__ __launch_bounds__(512, 4) void dense_mfma_kernel(
    const float* __restrict__ DF,
    const unsigned short* __restrict__ Aws,
    const float* __restrict__ b_ct,
    const float* __restrict__ gamma_dn,
    const float* __restrict__ beta_dn,
    const int2* __restrict__ idxws, const float2* __restrict__ wgtws,
    float* __restrict__ outd)
{
    int blk = blockIdx.x;
    int b   = blockIdx.y;
    int n0  = blk * 4;
    int S0  = n0 * 32;
    int T0  = n0 * 64;
    int tid  = threadIdx.x;
    int lane = tid & 63;
    int wid  = tid >> 6;
    int rit  = lane & 15;
    int kgrp = lane >> 4;

    __shared__ float Y[8 * 1024];
    __shared__ unsigned short Xs[146 * 128];
    __shared__ int2   sij[6];
    __shared__ float2 swt[6];
    __shared__ float bnb[128], bns[128], bnt[128];

    const float invs = 1.0f / sqrtf(1.0f + 1e-5f);
    if (tid < 128) {
        bnb[tid] = b_ct[tid];
        bns[tid] = gamma_dn[tid] * invs;
        bnt[tid] = beta_dn[tid];
    }
    if (tid < 6) {
        int s = n0 - 1 + tid;
        s = (s < 0) ? 0 : ((s > NBEF - 1) ? NBEF - 1 : s);
        sij[tid] = idxws[b * NBEF + s];
        swt[tid] = wgtws[b * NBEF + s];
    }
    if (tid < 256) {
        uint4 z = make_uint4(0, 0, 0, 0);
        *reinterpret_cast<uint4*>(&Xs[130 * 128 + tid * 8]) = z;
    }
    __syncthreads();

    const float* DFb = DF + (size_t)b * (DNIN * NSTK * NPNT);

    if (tid < 256) {
        int i    = tid & 127;
        int side = tid >> 7;
        int col  = side ? 129 : 0;
        int L    = side ? (S0 + 128) : (S0 - 1);
        L = (L < 0) ? 0 : ((L > 16383) ? 16383 : L);
        int stroke = L >> 5, pt = L & 31;
        int slot = stroke - (n0 - 1);
        int2  ij = sij[slot];
        float2 w = swt[slot];
        float v = w.x * DFb[(size_t)i * 8192 + (size_t)ij.x * NPNT + pt]
                + w.y * DFb[(size_t)i * 8192 + (size_t)ij.y * NPNT + pt];
        int dst = col * 128 + ((((i >> 3) ^ (col & 15))) << 3) + (i & 7);
        Xs[dst] = f32_to_bf16(v);
    }

    float* Ysl = &Y[wid * 1024];
    int swq = (lane & 7) ^ ((lane >> 3) & 7);
    int sp2 = lane & 31;
    int so  = lane >> 5;
    int goct = wid * 2 + so;
    #pragma unroll 1
    for (int nl = 0; nl < 4; ++nl) {
        int2 ij = sij[nl + 1];
        #pragma unroll
        for (int p = 0; p < 2; ++p) {
            int jj = p ? ij.y : ij.x;
            #pragma unroll
            for (int q = 0; q < 2; ++q) {
                int i = 16 * wid + q * 8 + (lane >> 3);
                const float* g = DFb + (size_t)i * 8192 + (size_t)jj * NPNT + (swq << 2);
                __builtin_amdgcn_global_load_lds((gas1_t)(const void*)g,
                    (las3_t)(void*)&Ysl[p * 512 + q * 256], 16, 0, 0);
            }
        }
        asm volatile("s_waitcnt vmcnt(0)" ::: "memory");
        __builtin_amdgcn_sched_barrier(0);
        {
            float2 w = swt[nl + 1];
            unsigned short t8[8];
            #pragma unroll
            for (int pp = 0; pp < 8; ++pp) {
                int a = (so * 8 + pp) * 32 + (((sp2 >> 2) ^ pp) << 2) + (sp2 & 3);
                float v = w.x * Ysl[a] + w.y * Ysl[512 + a];
                t8[pp] = f32_to_bf16(v);
            }
            int col = nl * 32 + sp2 + 1;
            int dst = col * 128 + ((goct ^ (col & 15)) << 3);
            *reinterpret_cast<uint4*>(&Xs[dst]) = *reinterpret_cast<const uint4*>(t8);
        }
    }
    __syncthreads();

    f32x4v acc[9][2];
    #pragma unroll
    for (int nt = 0; nt < 9; ++nt) {
        acc[nt][0] = (f32x4v){0.f, 0.f, 0.f, 0.f};
        acc[nt][1] = (f32x4v){0.f, 0.f, 0.f, 0.f};
    }
    #pragma unroll
    for (int kh = 0; kh < 2; ++kh) {
        bf16x8v af[2][4];
        #pragma unroll
        for (int mt = 0; mt < 2; ++mt) {
            int mt16 = wid + mt * 8;
            #pragma unroll
            for (int k4 = 0; k4 < 4; ++k4) {
                int ks = kh * 4 + k4;
                af[mt][k4] = *reinterpret_cast<const bf16x8v*>(
                    Aws + (((size_t)(mt16 * 8 + ks)) * 64 + lane) * 8);
            }
        }
        #pragma unroll
        for (int k4 = 0; k4 < 4; ++k4) {
            int ks   = kh * 4 + k4;
            int kb   = ks * 32 + kgrp * 8;
            int half = kb >> 7;
            int i    = kb & 127;
            #pragma unroll
            for (int nt = 0; nt < 9; ++nt) {
                int col = nt * 16 + rit + half;
                int srcx = col * 128 + ((((i >> 3) ^ (col & 15))) << 3);
                bf16x8v bfrag = *reinterpret_cast<const bf16x8v*>(&Xs[srcx]);
                acc[nt][0] = __builtin_amdgcn_mfma_f32_16x16x32_bf16(af[0][k4], bfrag, acc[nt][0], 0, 0, 0);
                acc[nt][1] = __builtin_amdgcn_mfma_f32_16x16x32_bf16(af[1][k4], bfrag, acc[nt][1], 0, 0, 0);
            }
        }
    }

    int srcl = (lane & 48) | ((lane + 1) & 15);
    #pragma unroll
    for (int nt = 0; nt < 9; ++nt) {
        int c = nt * 16 + rit;
        #pragma unroll
        for (int q = 0; q < 4; ++q) {
            float a1n = __shfl(acc[nt][1][q], srcl, 64);
            int o = wid * 16 + kgrp * 4 + q;
            float bias = bnb[o], scale = bns[o], beta = bnt[o];
            size_t rowbase = (((size_t)b * DNOUT + o) << 15) + (size_t)T0;
            if (c < 128) {
                float ye = fast_gelu((acc[nt][0][q] + bias) * scale + beta);
                if (rit < 15) {
                    float yo = fast_gelu((a1n + bias) * scale + beta);
                    *reinterpret_cast<float2*>(outd + rowbase + 2 * c) = make_float2(ye, yo);
                } else {
                    outd[rowbase + 2 * c] = ye;
                }
            }
            if (rit == 0 && c >= 1) {
                float yo0 = fast_gelu((acc[nt][1][q] + bias) * scale + beta);
                outd[rowbase + 2 * c - 1] = yo0;
            }
        }
    }
}

extern "C" void kernel_launch(void* const* d_in, const int* in_sizes, int n_in,
                              void* d_out, int out_size, void* d_ws, size_t ws_size,
                              hipStream_t stream) {
    const float* sparse_fea   = (const float*)d_in[0];
    const float* dense_fea    = (const float*)d_in[1];
    const float* stk_coor     = (const float*)d_in[2];
    const float* stk_coor_bef = (const float*)d_in[3];
    const float* w_sp     = (const float*)d_in[4];
    const float* b_sp     = (const float*)d_in[5];
    const float* gamma_sp = (const float*)d_in[6];
    const float* beta_sp  = (const float*)d_in[7];
    const float* w_ct     = (const float*)d_in[8];
    const float* b_ct     = (const float*)d_in[9];
    const float* gamma_dn = (const float*)d_in[10];
    const float* beta_dn  = (const float*)d_in[11];
    float* out = (float*)d_out;

    char* ws = (char*)d_ws;
    int2*   idx = (int2*)ws;                               // 64 KB
    float2* wgt = (float2*)(ws + 65536);                   // 64 KB
    unsigned short* Aws = (unsigned short*)(ws + 131072);  // 128 KB
    bool use_wt = (ws_size >= 786432);                     // + 512 KB wTq
    float4* wTq = use_wt ? (float4*)(ws + 262144) : nullptr;
    size_t xt_need = 786432 + (size_t)NB * XT_COLS * 128 * 2;  // ~68.0 MB
    bool use_xt = use_wt && (ws_size >= xt_need);
    unsigned short* XT = (unsigned short*)(ws + 786432);

    knn_kernel<<<dim3(NBEF / 16, NB), 256, 0, stream>>>(stk_coor, stk_coor_bef, idx, wgt);
    prep_a_kernel<<<32, 256, 0, stream>>>(w_ct, Aws);
    if (use_wt) prep_wt_kernel<<<128, 256, 0, stream>>>(w_sp, wTq);

    if (use_xt) {
        stage_xt_kernel<<<dim3(NBEF, NB), 256, 0, stream>>>(dense_fea, idx, wgt, XT);
        sparse_direct_kernel<<<dim3(NBEF / 8, NB), 256, 0, stream>>>(
            sparse_fea, w_sp, wTq, idx, wgt, b_sp, gamma_sp, beta_sp, out);
        dense_mfma2_kernel<<<dim3(128, NB), 512, 0, stream>>>(
            XT, Aws, b_ct, gamma_dn, beta_dn, out + SP_ELEMS);
    } else {
        sparse_direct_kernel<<<dim3(NBEF / 8, NB), 256, 0, stream>>>(
            sparse_fea, w_sp, wTq, idx, wgt, b_sp, gamma_sp, beta_sp, out);
        dense_mfma_kernel<<<dim3(NBEF / 4, NB), 512, 0, stream>>>(
            dense_fea, Aws, b_ct, gamma_dn, beta_dn, idx, wgt, out + SP_ELEMS);
    }
}

// Round 18
// 201.235 us; speedup vs baseline: 1.2775x; 1.2775x over previous
//
#include <hip/hip_runtime.h>
#include <math.h>

#define NB   16
#define NBEF 512
#define NSTK 256
#define CCO  128
#define SPIN 512
#define SPOUT 256
#define DNIN 128
#define DNOUT 128
#define NPNT 32
#define SP_ELEMS (NB * SPOUT * NBEF)   // 2,097,152 f32 elems (sparse output)

typedef __attribute__((ext_vector_type(8))) short bf16x8v;   // 8 bf16 = 4 VGPR
typedef __attribute__((ext_vector_type(4))) float f32x4v;    // MFMA C/D

typedef __attribute__((address_space(1))) const unsigned int* gas1_t;
typedef __attribute__((address_space(3))) unsigned int* las3_t;

__device__ __forceinline__ unsigned short f32_to_bf16(float f) {
    unsigned int u = __float_as_uint(f);
    u += 0x7fffu + ((u >> 16) & 1u);     // round-to-nearest-even
    return (unsigned short)(u >> 16);
}

// gelu(tanh approx) with hw exp2: tanh(z)=sign(z)*(1-2/(2^(2|z|*log2e)+1))
__device__ __forceinline__ float fast_gelu(float x) {
    float z = 0.7978845608028654f * x * (1.0f + 0.044715f * x * x);
    float az = fabsf(z) * 2.885390081777927f;   // 2*log2(e)
    float e;
    asm("v_exp_f32 %0, %1" : "=v"(e) : "v"(az));
    float r = __builtin_amdgcn_rcpf(e + 1.0f);
    float th = copysignf(1.0f - 2.0f * r, z);
    return 0.5f * x * (1.0f + th);
}

// order-preserving float -> uint map
__device__ __forceinline__ unsigned int f2ord(float f) {
    unsigned int u = __float_as_uint(f);
    return (u & 0x80000000u) ? ~u : (u | 0x80000000u);
}
__device__ __forceinline__ float ord2f(unsigned int o) {
    unsigned int u = (o & 0x80000000u) ? (o & 0x7fffffffu) : ~o;
    return __uint_as_float(u);
}

__device__ __forceinline__ unsigned long long wave_min_u64(unsigned long long k) {
    #pragma unroll
    for (int d = 32; d >= 1; d >>= 1) {
        unsigned long long o = __shfl_xor(k, d, 64);
        if (o < k) k = o;
    }
    return k;
}

// ---------------- Kernel 0: tiled 2-NN (v2 — measured best) ----------------
__global__ __launch_bounds__(256) void knn_kernel(
    const float* __restrict__ stk_coor,      // [B][256][128]
    const float* __restrict__ stk_coor_bef,  // [B][512][128]
    int2* __restrict__ idx_out,              // [B][512]
    float2* __restrict__ w_out)              // [B][512]
{
    int b  = blockIdx.y;
    int q0 = blockIdx.x * 16;
    int tid  = threadIdx.x;
    int lane = tid & 63;
    int qg   = tid >> 6;                     // wave id: queries qg*4..+4
    int pg   = lane;                         // points pg*4..+4

    __shared__ float Qt[128][16];            // [c][q] 8 KB
    __shared__ float Pt[32][260];            // [c-chunk][p] 33.3 KB (pad 4)

    {
        int q = tid >> 4, c0 = (tid & 15) * 8;
        const float* src = stk_coor_bef + ((size_t)b * NBEF + q0 + q) * CCO + c0;
        float4 v0 = *reinterpret_cast<const float4*>(src);
        float4 v1 = *reinterpret_cast<const float4*>(src + 4);
        Qt[c0+0][q] = v0.x; Qt[c0+1][q] = v0.y; Qt[c0+2][q] = v0.z; Qt[c0+3][q] = v0.w;
        Qt[c0+4][q] = v1.x; Qt[c0+5][q] = v1.y; Qt[c0+6][q] = v1.z; Qt[c0+7][q] = v1.w;
    }

    float dot[4][4];
    #pragma unroll
    for (int a = 0; a < 4; ++a)
        #pragma unroll
        for (int c = 0; c < 4; ++c) dot[a][c] = 0.f;
    float qn[4] = {0.f, 0.f, 0.f, 0.f};
    float pn[4] = {0.f, 0.f, 0.f, 0.f};

    for (int ct = 0; ct < 4; ++ct) {
        __syncthreads();
        #pragma unroll
        for (int it = 0; it < 8; ++it) {
            int p  = (tid >> 3) + it * 32;
            int cl = (tid & 7) * 4;
            float4 v = *reinterpret_cast<const float4*>(
                stk_coor + ((size_t)b * NSTK + p) * CCO + ct * 32 + cl);
            Pt[cl+0][p] = v.x; Pt[cl+1][p] = v.y; Pt[cl+2][p] = v.z; Pt[cl+3][p] = v.w;
        }
        __syncthreads();
        #pragma unroll 8
        for (int c = 0; c < 32; ++c) {
            float4 qv = *reinterpret_cast<const float4*>(&Qt[ct*32 + c][qg*4]);
            float4 pv = *reinterpret_cast<const float4*>(&Pt[c][pg*4]);
            float qa[4] = {qv.x, qv.y, qv.z, qv.w};
            float pa[4] = {pv.x, pv.y, pv.z, pv.w};
            #pragma unroll
            for (int j = 0; j < 4; ++j) {
                qn[j] += qa[j] * qa[j];
                pn[j] += pa[j] * pa[j];
                #pragma unroll
                for (int k = 0; k < 4; ++k) dot[j][k] += qa[j] * pa[k];
            }
        }
    }

    #pragma unroll
    for (int qj = 0; qj < 4; ++qj) {
        unsigned long long kA = 0xFFFFFFFFFFFFFFFFull, kB = 0xFFFFFFFFFFFFFFFFull;
        #pragma unroll
        for (int pj = 0; pj < 4; ++pj) {
            float d2 = qn[qj] + pn[pj] - 2.f * dot[qj][pj];
            unsigned long long key =
                ((unsigned long long)f2ord(d2) << 32) | (unsigned int)(pg * 4 + pj);
            if (key < kA)      { kB = kA; kA = key; }
            else if (key < kB) { kB = key; }
        }
        unsigned long long m0 = wave_min_u64(kA);
        unsigned long long c2 = (kA == m0) ? kB : kA;
        unsigned long long m1 = wave_min_u64(c2);
        if (lane == 0) {
            float d0 = ord2f((unsigned int)(m0 >> 32));
            float d1 = ord2f((unsigned int)(m1 >> 32));
            int j0 = (int)(m0 & 0xffffffffu), j1 = (int)(m1 & 0xffffffffu);
            float r0 = 1.f / (d0 + 1e-8f);
            float r1 = 1.f / (d1 + 1e-8f);
            float s = r0 + r1;
            int q = q0 + qg * 4 + qj;
            idx_out[b * NBEF + q] = make_int2(j0, j1);
            w_out[b * NBEF + q]   = make_float2(r0 / s, r1 / s);
        }
    }
}

// ---------------- Kernel 1: one-time A-matrix -> MFMA-fragment-linear bf16 ----------------
__global__ __launch_bounds__(256) void prep_a_kernel(
    const float* __restrict__ w_ct,          // [128][128][4]
    unsigned short* __restrict__ Aws)        // 65536 bf16
{
    int g = blockIdx.x * 256 + threadIdx.x;  // 0..8191
    int lane = g & 63;
    int ks = (g >> 6) & 7;
    int mt16 = g >> 9;
    int m = mt16 * 16 + (lane & 15);
    int o = m & 127;
    int modd = (m >= 128);
    unsigned short t8[8];
    #pragma unroll
    for (int j = 0; j < 8; ++j) {
        int k = ks * 32 + (lane >> 4) * 8 + j;
        int i = k & 127;
        int tap = modd ? (k < 128 ? 2 : 0) : (k < 128 ? 3 : 1);
        t8[j] = f32_to_bf16(w_ct[((size_t)i * DNOUT + o) * 4 + tap]);
    }
    *reinterpret_cast<uint4*>(Aws + (size_t)g * 8) = *reinterpret_cast<const uint4*>(t8);
}

// ---------------- Kernel 2: one-time w_sp quad-transpose -> wTq[c4][o] float4 ----------------
__global__ __launch_bounds__(256) void prep_wt_kernel(
    const float* __restrict__ w_sp,          // [256][512]
    float4* __restrict__ wTq)                // [128][256]
{
    int c4 = blockIdx.x;                     // 0..127
    int o  = threadIdx.x;                    // 0..255
    float4 v = *reinterpret_cast<const float4*>(w_sp + (size_t)o * SPIN + c4 * 4);
    wTq[c4 * 256 + o] = v;
}

// ---------------- Kernel A: fused sparse branch (R12 version — measured best) ----------------
__global__ __launch_bounds__(256) void sparse_direct_kernel(
    const float* __restrict__ SF,            // [16][512][256]
    const float* __restrict__ w_sp,          // [256][512] (fallback path)
    const float4* __restrict__ wTq,          // [128][256] transposed weights (or null)
    const int2* __restrict__ idxws, const float2* __restrict__ wgtws,
    const float* __restrict__ b_sp, const float* __restrict__ gamma_sp,
    const float* __restrict__ beta_sp,
    float* __restrict__ out)                 // [16][256][512] f32
{
    int b = blockIdx.y;
    int n0 = blockIdx.x * 8;                 // grid.x = 64
    int tid = threadIdx.x;

    __shared__ float fs[SPIN][8];            // 16 KB
    __shared__ int2   sij[8];
    __shared__ float2 swt[8];

    if (tid < 8) {
        sij[tid] = idxws[b * NBEF + n0 + tid];
        swt[tid] = wgtws[b * NBEF + n0 + tid];
    }
    __syncthreads();

    for (int l = tid; l < SPIN * 8; l += 256) {
        int c = l >> 3, nn = l & 7;
        int2  ij = sij[nn];
        float2 w = swt[nn];
        const float* row = SF + ((size_t)b * SPIN + c) * NSTK;
        fs[c][nn] = w.x * row[ij.x] + w.y * row[ij.y];
    }
    __syncthreads();

    int o = tid;
    float acc[8] = {0,0,0,0,0,0,0,0};
    if (wTq) {
        #pragma unroll 4
        for (int c4 = 0; c4 < SPIN / 4; ++c4) {
            float4 a = wTq[c4 * 256 + o];
            int c = c4 * 4;
            #pragma unroll
            for (int nn = 0; nn < 8; ++nn)
                acc[nn] += a.x * fs[c][nn] + a.y * fs[c+1][nn]
                         + a.z * fs[c+2][nn] + a.w * fs[c+3][nn];
        }
    } else {
        const float4* wr4 = reinterpret_cast<const float4*>(w_sp + (size_t)o * SPIN);
        #pragma unroll 4
        for (int c4 = 0; c4 < SPIN / 4; ++c4) {
            float4 a = wr4[c4];
            int c = c4 * 4;
            #pragma unroll
            for (int nn = 0; nn < 8; ++nn)
                acc[nn] += a.x * fs[c][nn] + a.y * fs[c+1][nn]
                         + a.z * fs[c+2][nn] + a.w * fs[c+3][nn];
        }
    }

    const float invs = 1.0f / sqrtf(1.0f + 1e-5f);
    float bias  = b_sp[o];
    float scale = gamma_sp[o] * invs;
    float beta  = beta_sp[o];
    float r[8];
    #pragma unroll
    for (int q = 0; q < 8; ++q)
        r[q] = fast_gelu((acc[q] + bias) * scale + beta);
    float* dst = out + ((size_t)b * SPOUT + o) * NBEF + n0;
    *reinterpret_cast<float4*>(dst)     = make_float4(r[0], r[1], r[2], r[3]);
    *reinterpret_cast<float4*>(dst + 4) = make_float4(r[4], r[5], r[6], r[7]);
}

// ---------------- Kernel B: dense branch via bf16 MFMA — seam-free full-line epilogue --------
// Staging: R16 barrier-free per-wave-slice DMA (measured best within noise).  MFMA: ks-outer,
// acc[9][2] resident.  NEW epilogue: for nt<8, each lane stores one ALIGNED float2
// {ye(2c), yo(2c+1)}, c = nt*16+rit.  yo needs C1[c+1]: source lane pre-selects
// (rit==0 ? acc[nt+1][1] : acc[nt][1]) so one shuffle delivers it for ALL lanes — no scalar
// seam stores, every 128-B t-segment written exactly once (WRITE_SIZE 378 -> ~268 MB).
__global__ __launch_bounds__(512, 4) void dense_mfma_kernel(
    const float* __restrict__ DF,            // [16][128][256][32]
    const unsigned short* __restrict__ Aws,  // fragment-linear A, 128 KB
    const float* __restrict__ b_ct,
    const float* __restrict__ gamma_dn,
    const float* __restrict__ beta_dn,
    const int2* __restrict__ idxws, const float2* __restrict__ wgtws,
    float* __restrict__ outd)                // [16][128][32768] f32 (already offset)
{
    int blk = blockIdx.x;                    // 0..127 (4 strokes each)
    int b   = blockIdx.y;
    int n0  = blk * 4;
    int S0  = n0 * 32;
    int T0  = n0 * 64;
    int tid  = threadIdx.x;
    int lane = tid & 63;
    int wid  = tid >> 6;                     // 0..7
    int rit  = lane & 15;
    int kgrp = lane >> 4;                    // 0..3

    __shared__ float Y[8 * 1024];            // 32 KB: per-wave slice [2][16][32] f32
    __shared__ unsigned short Xs[146 * 128]; // 37.4 KB
    __shared__ int2   sij[6];
    __shared__ float2 swt[6];
    __shared__ float bnb[128], bns[128], bnt[128];

    const float invs = 1.0f / sqrtf(1.0f + 1e-5f);
    if (tid < 128) {
        bnb[tid] = b_ct[tid];
        bns[tid] = gamma_dn[tid] * invs;
        bnt[tid] = beta_dn[tid];
    }
    if (tid < 6) {
        int s = n0 - 1 + tid;
        s = (s < 0) ? 0 : ((s > NBEF - 1) ? NBEF - 1 : s);
        sij[tid] = idxws[b * NBEF + s];
        swt[tid] = wgtws[b * NBEF + s];
    }
    // zero-fill pad cols 130..145
    if (tid < 256) {
        uint4 z = make_uint4(0, 0, 0, 0);
        *reinterpret_cast<uint4*>(&Xs[130 * 128 + tid * 8]) = z;
    }
    __syncthreads();                         // barrier 1

    const float* DFb = DF + (size_t)b * (DNIN * NSTK * NPNT);

    // halo cols 0 and 129
    if (tid < 256) {
        int i    = tid & 127;
        int side = tid >> 7;
        int col  = side ? 129 : 0;
        int L    = side ? (S0 + 128) : (S0 - 1);
        L = (L < 0) ? 0 : ((L > 16383) ? 16383 : L);
        int stroke = L >> 5, pt = L & 31;
        int slot = stroke - (n0 - 1);
        int2  ij = sij[slot];
        float2 w = swt[slot];
        float v = w.x * DFb[(size_t)i * 8192 + (size_t)ij.x * NPNT + pt]
                + w.y * DFb[(size_t)i * 8192 + (size_t)ij.y * NPNT + pt];
        int dst = col * 128 + ((((i >> 3) ^ (col & 15))) << 3) + (i & 7);
        Xs[dst] = f32_to_bf16(v);
    }

    // barrier-free per-wave staging
    float* Ysl = &Y[wid * 1024];
    int swq = (lane & 7) ^ ((lane >> 3) & 7);
    int sp2 = lane & 31;
    int so  = lane >> 5;
    int goct = wid * 2 + so;
    #pragma unroll 1
    for (int nl = 0; nl < 4; ++nl) {
        int2 ij = sij[nl + 1];
        #pragma unroll
        for (int p = 0; p < 2; ++p) {
            int jj = p ? ij.y : ij.x;
            #pragma unroll
            for (int q = 0; q < 2; ++q) {
                int i = 16 * wid + q * 8 + (lane >> 3);
                const float* g = DFb + (size_t)i * 8192 + (size_t)jj * NPNT + (swq << 2);
                __builtin_amdgcn_global_load_lds((gas1_t)(const void*)g,
                    (las3_t)(void*)&Ysl[p * 512 + q * 256], 16, 0, 0);
            }
        }
        asm volatile("s_waitcnt vmcnt(0)" ::: "memory");
        __builtin_amdgcn_sched_barrier(0);
        {
            float2 w = swt[nl + 1];
            unsigned short t8[8];
            #pragma unroll
            for (int pp = 0; pp < 8; ++pp) {
                int a = (so * 8 + pp) * 32 + (((sp2 >> 2) ^ pp) << 2) + (sp2 & 3);
                float v = w.x * Ysl[a] + w.y * Ysl[512 + a];
                t8[pp] = f32_to_bf16(v);
            }
            int col = nl * 32 + sp2 + 1;
            int dst = col * 128 + ((goct ^ (col & 15)) << 3);
            *reinterpret_cast<uint4*>(&Xs[dst]) = *reinterpret_cast<const uint4*>(t8);
        }
    }
    __syncthreads();                         // barrier 2: Xs ready

    // MFMA: ks-outer / nt-inner, acc[9][2] resident
    f32x4v acc[9][2];
    #pragma unroll
    for (int nt = 0; nt < 9; ++nt) {
        acc[nt][0] = (f32x4v){0.f, 0.f, 0.f, 0.f};
        acc[nt][1] = (f32x4v){0.f, 0.f, 0.f, 0.f};
    }
    #pragma unroll
    for (int kh = 0; kh < 2; ++kh) {
        bf16x8v af[2][4];
        #pragma unroll
        for (int mt = 0; mt < 2; ++mt) {
            int mt16 = wid + mt * 8;
            #pragma unroll
            for (int k4 = 0; k4 < 4; ++k4) {
                int ks = kh * 4 + k4;
                af[mt][k4] = *reinterpret_cast<const bf16x8v*>(
                    Aws + (((size_t)(mt16 * 8 + ks)) * 64 + lane) * 8);
            }
        }
        #pragma unroll
        for (int k4 = 0; k4 < 4; ++k4) {
            int ks   = kh * 4 + k4;
            int kb   = ks * 32 + kgrp * 8;
            int half = kb >> 7;
            int i    = kb & 127;
            #pragma unroll
            for (int nt = 0; nt < 9; ++nt) {
                int col = nt * 16 + rit + half;
                int src = col * 128 + ((((i >> 3) ^ (col & 15))) << 3);
                bf16x8v bfrag = *reinterpret_cast<const bf16x8v*>(&Xs[src]);
                acc[nt][0] = __builtin_amdgcn_mfma_f32_16x16x32_bf16(af[0][k4], bfrag, acc[nt][0], 0, 0, 0);
                acc[nt][1] = __builtin_amdgcn_mfma_f32_16x16x32_bf16(af[1][k4], bfrag, acc[nt][1], 0, 0, 0);
            }
        }
    }

    // ---- seam-free epilogue: nt<8, full aligned float2 per lane ----
    int srcl = (lane & 48) | ((lane + 1) & 15);
    #pragma unroll
    for (int nt = 0; nt < 8; ++nt) {
        int c = nt * 16 + rit;               // always < 128
        #pragma unroll
        for (int q = 0; q < 4; ++q) {
            // source lane rit_s provides acc[nt+1][1] if rit_s==0 (consumer rit==15), else acc[nt][1]
            float srcv = (rit == 0) ? acc[nt + 1][1][q] : acc[nt][1][q];
            float a1n = __shfl(srcv, srcl, 64);           // C1[c+1] for every lane
            int o = wid * 16 + kgrp * 4 + q;              // C/D row = (lane>>4)*4+q
            float bias = bnb[o], scale = bns[o], beta = bnt[o];
            float ye = fast_gelu((acc[nt][0][q] + bias) * scale + beta);
            float yo = fast_gelu((a1n + bias) * scale + beta);
            size_t rowbase = (((size_t)b * DNOUT + o) << 15) + (size_t)T0;
            *reinterpret_cast<float2*>(outd + rowbase + 2 * c) = make_float2(ye, yo);
        }
    }
}

extern "C" void kernel_launch(void* const* d_in, const int* in_sizes, int n_in,
                              void* d_out, int out_size, void* d_ws, size_t ws_size,
                              hipStream_t stream) {
    const float* sparse_fea   = (const float*)d_in[0];
    const float* dense_fea    = (const float*)d_in[1];
    const float* stk_coor     = (const float*)d_in[2];
    const float* stk_coor_bef = (const float*)d_in[3];
    const float* w_sp     = (const float*)d_in[4];
    const float* b_sp     = (const float*)d_in[5];
    const float* gamma_sp = (const float*)d_in[6];
    const float* beta_sp  = (const float*)d_in[7];
    const float* w_ct     = (const float*)d_in[8];
    const float* b_ct     = (const float*)d_in[9];
    const float* gamma_dn = (const float*)d_in[10];
    const float* beta_dn  = (const float*)d_in[11];
    float* out = (float*)d_out;

    char* ws = (char*)d_ws;
    int2*   idx = (int2*)ws;                               // 64 KB
    float2* wgt = (float2*)(ws + 65536);                   // 64 KB
    unsigned short* Aws = (unsigned short*)(ws + 131072);  // 128 KB
    bool use_wt = (ws_size >= 786432);                     // + 512 KB wTq = 768 KB total
    float4* wTq = use_wt ? (float4*)(ws + 262144) : nullptr;

    knn_kernel<<<dim3(NBEF / 16, NB), 256, 0, stream>>>(stk_coor, stk_coor_bef, idx, wgt);
    prep_a_kernel<<<32, 256, 0, stream>>>(w_ct, Aws);
    if (use_wt) prep_wt_kernel<<<128, 256, 0, stream>>>(w_sp, wTq);
    sparse_direct_kernel<<<dim3(NBEF / 8, NB), 256, 0, stream>>>(
        sparse_fea, w_sp, wTq, idx, wgt, b_sp, gamma_sp, beta_sp, out);
    dense_mfma_kernel<<<dim3(NBEF / 4, NB), 512, 0, stream>>>(
        dense_fea, Aws, b_ct, gamma_dn, beta_dn, idx, wgt, out + SP_ELEMS);
}

// Round 19
// 194.409 us; speedup vs baseline: 1.3223x; 1.0351x over previous
//
#include <hip/hip_runtime.h>
#include <math.h>

#define NB   16
#define NBEF 512
#define NSTK 256
#define CCO  128
#define SPIN 512
#define SPOUT 256
#define DNIN 128
#define DNOUT 128
#define NPNT 32
#define SP_ELEMS (NB * SPOUT * NBEF)   // 2,097,152 f32 elems (sparse output)

typedef __attribute__((ext_vector_type(8))) short bf16x8v;   // 8 bf16 = 4 VGPR
typedef __attribute__((ext_vector_type(4))) float f32x4v;    // MFMA C/D

typedef __attribute__((address_space(1))) const unsigned int* gas1_t;
typedef __attribute__((address_space(3))) unsigned int* las3_t;

__device__ __forceinline__ unsigned short f32_to_bf16(float f) {
    unsigned int u = __float_as_uint(f);
    u += 0x7fffu + ((u >> 16) & 1u);     // round-to-nearest-even
    return (unsigned short)(u >> 16);
}

// gelu(tanh approx) with hw exp2: tanh(z)=sign(z)*(1-2/(2^(2|z|*log2e)+1))
__device__ __forceinline__ float fast_gelu(float x) {
    float z = 0.7978845608028654f * x * (1.0f + 0.044715f * x * x);
    float az = fabsf(z) * 2.885390081777927f;   // 2*log2(e)
    float e;
    asm("v_exp_f32 %0, %1" : "=v"(e) : "v"(az));
    float r = __builtin_amdgcn_rcpf(e + 1.0f);
    float th = copysignf(1.0f - 2.0f * r, z);
    return 0.5f * x * (1.0f + th);
}

// order-preserving float -> uint map
__device__ __forceinline__ unsigned int f2ord(float f) {
    unsigned int u = __float_as_uint(f);
    return (u & 0x80000000u) ? ~u : (u | 0x80000000u);
}
__device__ __forceinline__ float ord2f(unsigned int o) {
    unsigned int u = (o & 0x80000000u) ? (o & 0x7fffffffu) : ~o;
    return __uint_as_float(u);
}

__device__ __forceinline__ unsigned long long wave_min_u64(unsigned long long k) {
    #pragma unroll
    for (int d = 32; d >= 1; d >>= 1) {
        unsigned long long o = __shfl_xor(k, d, 64);
        if (o < k) k = o;
    }
    return k;
}

// ---------------- Kernel 0: tiled 2-NN (v2 — measured best) ----------------
__global__ __launch_bounds__(256) void knn_kernel(
    const float* __restrict__ stk_coor,      // [B][256][128]
    const float* __restrict__ stk_coor_bef,  // [B][512][128]
    int2* __restrict__ idx_out,              // [B][512]
    float2* __restrict__ w_out)              // [B][512]
{
    int b  = blockIdx.y;
    int q0 = blockIdx.x * 16;
    int tid  = threadIdx.x;
    int lane = tid & 63;
    int qg   = tid >> 6;                     // wave id: queries qg*4..+4
    int pg   = lane;                         // points pg*4..+4

    __shared__ float Qt[128][16];            // [c][q] 8 KB
    __shared__ float Pt[32][260];            // [c-chunk][p] 33.3 KB (pad 4)

    {
        int q = tid >> 4, c0 = (tid & 15) * 8;
        const float* src = stk_coor_bef + ((size_t)b * NBEF + q0 + q) * CCO + c0;
        float4 v0 = *reinterpret_cast<const float4*>(src);
        float4 v1 = *reinterpret_cast<const float4*>(src + 4);
        Qt[c0+0][q] = v0.x; Qt[c0+1][q] = v0.y; Qt[c0+2][q] = v0.z; Qt[c0+3][q] = v0.w;
        Qt[c0+4][q] = v1.x; Qt[c0+5][q] = v1.y; Qt[c0+6][q] = v1.z; Qt[c0+7][q] = v1.w;
    }

    float dot[4][4];
    #pragma unroll
    for (int a = 0; a < 4; ++a)
        #pragma unroll
        for (int c = 0; c < 4; ++c) dot[a][c] = 0.f;
    float qn[4] = {0.f, 0.f, 0.f, 0.f};
    float pn[4] = {0.f, 0.f, 0.f, 0.f};

    for (int ct = 0; ct < 4; ++ct) {
        __syncthreads();
        #pragma unroll
        for (int it = 0; it < 8; ++it) {
            int p  = (tid >> 3) + it * 32;
            int cl = (tid & 7) * 4;
            float4 v = *reinterpret_cast<const float4*>(
                stk_coor + ((size_t)b * NSTK + p) * CCO + ct * 32 + cl);
            Pt[cl+0][p] = v.x; Pt[cl+1][p] = v.y; Pt[cl+2][p] = v.z; Pt[cl+3][p] = v.w;
        }
        __syncthreads();
        #pragma unroll 8
        for (int c = 0; c < 32; ++c) {
            float4 qv = *reinterpret_cast<const float4*>(&Qt[ct*32 + c][qg*4]);
            float4 pv = *reinterpret_cast<const float4*>(&Pt[c][pg*4]);
            float qa[4] = {qv.x, qv.y, qv.z, qv.w};
            float pa[4] = {pv.x, pv.y, pv.z, pv.w};
            #pragma unroll
            for (int j = 0; j < 4; ++j) {
                qn[j] += qa[j] * qa[j];
                pn[j] += pa[j] * pa[j];
                #pragma unroll
                for (int k = 0; k < 4; ++k) dot[j][k] += qa[j] * pa[k];
            }
        }
    }

    #pragma unroll
    for (int qj = 0; qj < 4; ++qj) {
        unsigned long long kA = 0xFFFFFFFFFFFFFFFFull, kB = 0xFFFFFFFFFFFFFFFFull;
        #pragma unroll
        for (int pj = 0; pj < 4; ++pj) {
            float d2 = qn[qj] + pn[pj] - 2.f * dot[qj][pj];
            unsigned long long key =
                ((unsigned long long)f2ord(d2) << 32) | (unsigned int)(pg * 4 + pj);
            if (key < kA)      { kB = kA; kA = key; }
            else if (key < kB) { kB = key; }
        }
        unsigned long long m0 = wave_min_u64(kA);
        unsigned long long c2 = (kA == m0) ? kB : kA;
        unsigned long long m1 = wave_min_u64(c2);
        if (lane == 0) {
            float d0 = ord2f((unsigned int)(m0 >> 32));
            float d1 = ord2f((unsigned int)(m1 >> 32));
            int j0 = (int)(m0 & 0xffffffffu), j1 = (int)(m1 & 0xffffffffu);
            float r0 = 1.f / (d0 + 1e-8f);
            float r1 = 1.f / (d1 + 1e-8f);
            float s = r0 + r1;
            int q = q0 + qg * 4 + qj;
            idx_out[b * NBEF + q] = make_int2(j0, j1);
            w_out[b * NBEF + q]   = make_float2(r0 / s, r1 / s);
        }
    }
}

// ---------------- Kernel 1: one-time A-matrix -> MFMA-fragment-linear bf16 ----------------
__global__ __launch_bounds__(256) void prep_a_kernel(
    const float* __restrict__ w_ct,          // [128][128][4]
    unsigned short* __restrict__ Aws)        // 65536 bf16
{
    int g = blockIdx.x * 256 + threadIdx.x;  // 0..8191
    int lane = g & 63;
    int ks = (g >> 6) & 7;
    int mt16 = g >> 9;
    int m = mt16 * 16 + (lane & 15);
    int o = m & 127;
    int modd = (m >= 128);
    unsigned short t8[8];
    #pragma unroll
    for (int j = 0; j < 8; ++j) {
        int k = ks * 32 + (lane >> 4) * 8 + j;
        int i = k & 127;
        int tap = modd ? (k < 128 ? 2 : 0) : (k < 128 ? 3 : 1);
        t8[j] = f32_to_bf16(w_ct[((size_t)i * DNOUT + o) * 4 + tap]);
    }
    *reinterpret_cast<uint4*>(Aws + (size_t)g * 8) = *reinterpret_cast<const uint4*>(t8);
}

// ---------------- Kernel 2: one-time w_sp quad-transpose -> wTq[c4][o] float4 ----------------
__global__ __launch_bounds__(256) void prep_wt_kernel(
    const float* __restrict__ w_sp,          // [256][512]
    float4* __restrict__ wTq)                // [128][256]
{
    int c4 = blockIdx.x;                     // 0..127
    int o  = threadIdx.x;                    // 0..255
    float4 v = *reinterpret_cast<const float4*>(w_sp + (size_t)o * SPIN + c4 * 4);
    wTq[c4 * 256 + o] = v;
}

// ---------------- Kernel A: fused sparse branch — b128-vectorized fs reads ----------------
// Inner loop LDS traffic: 8 ds_read_b128 per c4 (fA/fB) instead of 32 ds_read_b32 broadcasts
// (sparse was LDS-issue-bound: 4096 scalar reads/wave ≈ 24K cycles).  Same 4-term-per-c4
// accumulation grouping; wTq coalesced weight path unchanged.
__global__ __launch_bounds__(256) void sparse_direct_kernel(
    const float* __restrict__ SF,            // [16][512][256]
    const float* __restrict__ w_sp,          // [256][512] (fallback path)
    const float4* __restrict__ wTq,          // [128][256] transposed weights (or null)
    const int2* __restrict__ idxws, const float2* __restrict__ wgtws,
    const float* __restrict__ b_sp, const float* __restrict__ gamma_sp,
    const float* __restrict__ beta_sp,
    float* __restrict__ out)                 // [16][256][512] f32
{
    int b = blockIdx.y;
    int n0 = blockIdx.x * 8;                 // grid.x = 64
    int tid = threadIdx.x;

    __shared__ float fs[SPIN][8];            // 16 KB
    __shared__ int2   sij[8];
    __shared__ float2 swt[8];

    if (tid < 8) {
        sij[tid] = idxws[b * NBEF + n0 + tid];
        swt[tid] = wgtws[b * NBEF + n0 + tid];
    }
    __syncthreads();

    for (int l = tid; l < SPIN * 8; l += 256) {
        int c = l >> 3, nn = l & 7;
        int2  ij = sij[nn];
        float2 w = swt[nn];
        const float* row = SF + ((size_t)b * SPIN + c) * NSTK;
        fs[c][nn] = w.x * row[ij.x] + w.y * row[ij.y];
    }
    __syncthreads();

    int o = tid;
    float acc[8] = {0,0,0,0,0,0,0,0};
    #pragma unroll 2
    for (int c4 = 0; c4 < SPIN / 4; ++c4) {
        float4 a = wTq ? wTq[c4 * 256 + o]
                       : *reinterpret_cast<const float4*>(w_sp + (size_t)o * SPIN + c4 * 4);
        int c = c4 * 4;
        float4 fA[4], fB[4];                 // fs rows c..c+3, halves [0..3],[4..7]
        #pragma unroll
        for (int k = 0; k < 4; ++k) {
            fA[k] = *reinterpret_cast<const float4*>(&fs[c + k][0]);
            fB[k] = *reinterpret_cast<const float4*>(&fs[c + k][4]);
        }
        const float* a4 = reinterpret_cast<const float*>(&a);
        #pragma unroll
        for (int nn = 0; nn < 4; ++nn) {
            float sA = 0.f, sB = 0.f;
            #pragma unroll
            for (int k = 0; k < 4; ++k) {
                sA += a4[k] * reinterpret_cast<const float*>(&fA[k])[nn];
                sB += a4[k] * reinterpret_cast<const float*>(&fB[k])[nn];
            }
            acc[nn]     += sA;
            acc[nn + 4] += sB;
        }
    }

    const float invs = 1.0f / sqrtf(1.0f + 1e-5f);
    float bias  = b_sp[o];
    float scale = gamma_sp[o] * invs;
    float beta  = beta_sp[o];
    float r[8];
    #pragma unroll
    for (int q = 0; q < 8; ++q)
        r[q] = fast_gelu((acc[q] + bias) * scale + beta);
    float* dst = out + ((size_t)b * SPOUT + o) * NBEF + n0;
    *reinterpret_cast<float4*>(dst)     = make_float4(r[0], r[1], r[2], r[3]);
    *reinterpret_cast<float4*>(dst + 4) = make_float4(r[4], r[5], r[6], r[7]);
}

// ---------------- Kernel B: dense branch via bf16 MFMA — seam-free full-line epilogue --------
// (R18 winner — unchanged.)  Staging: barrier-free per-wave-slice DMA.  MFMA: ks-outer,
// acc[9][2] resident.  Epilogue: nt<8, each lane stores one ALIGNED float2 {ye(2c), yo(2c+1)};
// yo's C1[c+1] via one shuffle with source-lane pre-select (rit==0 ? acc[nt+1][1] : acc[nt][1]).
__global__ __launch_bounds__(512, 4) void dense_mfma_kernel(
    const float* __restrict__ DF,            // [16][128][256][32]
    const unsigned short* __restrict__ Aws,  // fragment-linear A, 128 KB
    const float* __restrict__ b_ct,
    const float* __restrict__ gamma_dn,
    const float* __restrict__ beta_dn,
    const int2* __restrict__ idxws, const float2* __restrict__ wgtws,
    float* __restrict__ outd)                // [16][128][32768] f32 (already offset)
{
    int blk = blockIdx.x;                    // 0..127 (4 strokes each)
    int b   = blockIdx.y;
    int n0  = blk * 4;
    int S0  = n0 * 32;
    int T0  = n0 * 64;
    int tid  = threadIdx.x;
    int lane = tid & 63;
    int wid  = tid >> 6;                     // 0..7
    int rit  = lane & 15;
    int kgrp = lane >> 4;                    // 0..3

    __shared__ float Y[8 * 1024];            // 32 KB: per-wave slice [2][16][32] f32
    __shared__ unsigned short Xs[146 * 128]; // 37.4 KB
    __shared__ int2   sij[6];
    __shared__ float2 swt[6];
    __shared__ float bnb[128], bns[128], bnt[128];

    const float invs = 1.0f / sqrtf(1.0f + 1e-5f);
    if (tid < 128) {
        bnb[tid] = b_ct[tid];
        bns[tid] = gamma_dn[tid] * invs;
        bnt[tid] = beta_dn[tid];
    }
    if (tid < 6) {
        int s = n0 - 1 + tid;
        s = (s < 0) ? 0 : ((s > NBEF - 1) ? NBEF - 1 : s);
        sij[tid] = idxws[b * NBEF + s];
        swt[tid] = wgtws[b * NBEF + s];
    }
    // zero-fill pad cols 130..145
    if (tid < 256) {
        uint4 z = make_uint4(0, 0, 0, 0);
        *reinterpret_cast<uint4*>(&Xs[130 * 128 + tid * 8]) = z;
    }
    __syncthreads();                         // barrier 1

    const float* DFb = DF + (size_t)b * (DNIN * NSTK * NPNT);

    // halo cols 0 and 129
    if (tid < 256) {
        int i    = tid & 127;
        int side = tid >> 7;
        int col  = side ? 129 : 0;
        int L    = side ? (S0 + 128) : (S0 - 1);
        L = (L < 0) ? 0 : ((L > 16383) ? 16383 : L);
        int stroke = L >> 5, pt = L & 31;
        int slot = stroke - (n0 - 1);
        int2  ij = sij[slot];
        float2 w = swt[slot];
        float v = w.x * DFb[(size_t)i * 8192 + (size_t)ij.x * NPNT + pt]
                + w.y * DFb[(size_t)i * 8192 + (size_t)ij.y * NPNT + pt];
        int dst = col * 128 + ((((i >> 3) ^ (col & 15))) << 3) + (i & 7);
        Xs[dst] = f32_to_bf16(v);
    }

    // barrier-free per-wave staging
    float* Ysl = &Y[wid * 1024];
    int swq = (lane & 7) ^ ((lane >> 3) & 7);
    int sp2 = lane & 31;
    int so  = lane >> 5;
    int goct = wid * 2 + so;
    #pragma unroll 1
    for (int nl = 0; nl < 4; ++nl) {
        int2 ij = sij[nl + 1];
        #pragma unroll
        for (int p = 0; p < 2; ++p) {
            int jj = p ? ij.y : ij.x;
            #pragma unroll
            for (int q = 0; q < 2; ++q) {
                int i = 16 * wid + q * 8 + (lane >> 3);
                const float* g = DFb + (size_t)i * 8192 + (size_t)jj * NPNT + (swq << 2);
                __builtin_amdgcn_global_load_lds((gas1_t)(const void*)g,
                    (las3_t)(void*)&Ysl[p * 512 + q * 256], 16, 0, 0);
            }
        }
        asm volatile("s_waitcnt vmcnt(0)" ::: "memory");
        __builtin_amdgcn_sched_barrier(0);
        {
            float2 w = swt[nl + 1];
            unsigned short t8[8];
            #pragma unroll
            for (int pp = 0; pp < 8; ++pp) {
                int a = (so * 8 + pp) * 32 + (((sp2 >> 2) ^ pp) << 2) + (sp2 & 3);
                float v = w.x * Ysl[a] + w.y * Ysl[512 + a];
                t8[pp] = f32_to_bf16(v);
            }
            int col = nl * 32 + sp2 + 1;
            int dst = col * 128 + ((goct ^ (col & 15)) << 3);
            *reinterpret_cast<uint4*>(&Xs[dst]) = *reinterpret_cast<const uint4*>(t8);
        }
    }
    __syncthreads();                         // barrier 2: Xs ready

    // MFMA: ks-outer / nt-inner, acc[9][2] resident
    f32x4v acc[9][2];
    #pragma unroll
    for (int nt = 0; nt < 9; ++nt) {
        acc[nt][0] = (f32x4v){0.f, 0.f, 0.f, 0.f};
        acc[nt][1] = (f32x4v){0.f, 0.f, 0.f, 0.f};
    }
    #pragma unroll
    for (int kh = 0; kh < 2; ++kh) {
        bf16x8v af[2][4];
        #pragma unroll
        for (int mt = 0; mt < 2; ++mt) {
            int mt16 = wid + mt * 8;
            #pragma unroll
            for (int k4 = 0; k4 < 4; ++k4) {
                int ks = kh * 4 + k4;
                af[mt][k4] = *reinterpret_cast<const bf16x8v*>(
                    Aws + (((size_t)(mt16 * 8 + ks)) * 64 + lane) * 8);
            }
        }
        #pragma unroll
        for (int k4 = 0; k4 < 4; ++k4) {
            int ks   = kh * 4 + k4;
            int kb   = ks * 32 + kgrp * 8;
            int half = kb >> 7;
            int i    = kb & 127;
            #pragma unroll
            for (int nt = 0; nt < 9; ++nt) {
                int col = nt * 16 + rit + half;
                int src = col * 128 + ((((i >> 3) ^ (col & 15))) << 3);
                bf16x8v bfrag = *reinterpret_cast<const bf16x8v*>(&Xs[src]);
                acc[nt][0] = __builtin_amdgcn_mfma_f32_16x16x32_bf16(af[0][k4], bfrag, acc[nt][0], 0, 0, 0);
                acc[nt][1] = __builtin_amdgcn_mfma_f32_16x16x32_bf16(af[1][k4], bfrag, acc[nt][1], 0, 0, 0);
            }
        }
    }

    // seam-free epilogue: nt<8, full aligned float2 per lane
    int srcl = (lane & 48) | ((lane + 1) & 15);
    #pragma unroll
    for (int nt = 0; nt < 8; ++nt) {
        int c = nt * 16 + rit;               // always < 128
        #pragma unroll
        for (int q = 0; q < 4; ++q) {
            float srcv = (rit == 0) ? acc[nt + 1][1][q] : acc[nt][1][q];
            float a1n = __shfl(srcv, srcl, 64);           // C1[c+1] for every lane
            int o = wid * 16 + kgrp * 4 + q;              // C/D row = (lane>>4)*4+q
            float bias = bnb[o], scale = bns[o], beta = bnt[o];
            float ye = fast_gelu((acc[nt][0][q] + bias) * scale + beta);
            float yo = fast_gelu((a1n + bias) * scale + beta);
            size_t rowbase = (((size_t)b * DNOUT + o) << 15) + (size_t)T0;
            *reinterpret_cast<float2*>(outd + rowbase + 2 * c) = make_float2(ye, yo);
        }
    }
}

extern "C" void kernel_launch(void* const* d_in, const int* in_sizes, int n_in,
                              void* d_out, int out_size, void* d_ws, size_t ws_size,
                              hipStream_t stream) {
    const float* sparse_fea   = (const float*)d_in[0];
    const float* dense_fea    = (const float*)d_in[1];
    const float* stk_coor     = (const float*)d_in[2];
    const float* stk_coor_bef = (const float*)d_in[3];
    const float* w_sp     = (const float*)d_in[4];
    const float* b_sp     = (const float*)d_in[5];
    const float* gamma_sp = (const float*)d_in[6];
    const float* beta_sp  = (const float*)d_in[7];
    const float* w_ct     = (const float*)d_in[8];
    const float* b_ct     = (const float*)d_in[9];
    const float* gamma_dn = (const float*)d_in[10];
    const float* beta_dn  = (const float*)d_in[11];
    float* out = (float*)d_out;

    char* ws = (char*)d_ws;
    int2*   idx = (int2*)ws;                               // 64 KB
    float2* wgt = (float2*)(ws + 65536);                   // 64 KB
    unsigned short* Aws = (unsigned short*)(ws + 131072);  // 128 KB
    bool use_wt = (ws_size >= 786432);                     // + 512 KB wTq = 768 KB total
    float4* wTq = use_wt ? (float4*)(ws + 262144) : nullptr;

    knn_kernel<<<dim3(NBEF / 16, NB), 256, 0, stream>>>(stk_coor, stk_coor_bef, idx, wgt);
    prep_a_kernel<<<32, 256, 0, stream>>>(w_ct, Aws);
    if (use_wt) prep_wt_kernel<<<128, 256, 0, stream>>>(w_sp, wTq);
    sparse_direct_kernel<<<dim3(NBEF / 8, NB), 256, 0, stream>>>(
        sparse_fea, w_sp, wTq, idx, wgt, b_sp, gamma_sp, beta_sp, out);
    dense_mfma_kernel<<<dim3(NBEF / 4, NB), 512, 0, stream>>>(
        dense_fea, Aws, b_ct, gamma_dn, beta_dn, idx, wgt, out + SP_ELEMS);
}

// Round 20
// 187.718 us; speedup vs baseline: 1.3694x; 1.0356x over previous
//
#include <hip/hip_runtime.h>
#include <math.h>

#define NB   16
#define NBEF 512
#define NSTK 256
#define CCO  128
#define SPIN 512
#define SPOUT 256
#define DNIN 128
#define DNOUT 128
#define NPNT 32
#define SP_ELEMS (NB * SPOUT * NBEF)   // 2,097,152 f32 elems (sparse output)

typedef __attribute__((ext_vector_type(8))) short bf16x8v;   // 8 bf16 = 4 VGPR
typedef __attribute__((ext_vector_type(4))) float f32x4v;    // MFMA C/D

typedef __attribute__((address_space(1))) const unsigned int* gas1_t;
typedef __attribute__((address_space(3))) unsigned int* las3_t;

__device__ __forceinline__ unsigned short f32_to_bf16(float f) {
    unsigned int u = __float_as_uint(f);
    u += 0x7fffu + ((u >> 16) & 1u);     // round-to-nearest-even
    return (unsigned short)(u >> 16);
}

// gelu(tanh approx) with hw exp2: tanh(z)=sign(z)*(1-2/(2^(2|z|*log2e)+1))
__device__ __forceinline__ float fast_gelu(float x) {
    float z = 0.7978845608028654f * x * (1.0f + 0.044715f * x * x);
    float az = fabsf(z) * 2.885390081777927f;   // 2*log2(e)
    float e;
    asm("v_exp_f32 %0, %1" : "=v"(e) : "v"(az));
    float r = __builtin_amdgcn_rcpf(e + 1.0f);
    float th = copysignf(1.0f - 2.0f * r, z);
    return 0.5f * x * (1.0f + th);
}

// order-preserving float -> uint map
__device__ __forceinline__ unsigned int f2ord(float f) {
    unsigned int u = __float_as_uint(f);
    return (u & 0x80000000u) ? ~u : (u | 0x80000000u);
}
__device__ __forceinline__ float ord2f(unsigned int o) {
    unsigned int u = (o & 0x80000000u) ? (o & 0x7fffffffu) : ~o;
    return __uint_as_float(u);
}

__device__ __forceinline__ unsigned long long wave_min_u64(unsigned long long k) {
    #pragma unroll
    for (int d = 32; d >= 1; d >>= 1) {
        unsigned long long o = __shfl_xor(k, d, 64);
        if (o < k) k = o;
    }
    return k;
}

// ---------------- Kernel 0: tiled 2-NN (v2 — measured best) ----------------
__global__ __launch_bounds__(256) void knn_kernel(
    const float* __restrict__ stk_coor,      // [B][256][128]
    const float* __restrict__ stk_coor_bef,  // [B][512][128]
    int2* __restrict__ idx_out,              // [B][512]
    float2* __restrict__ w_out)              // [B][512]
{
    int b  = blockIdx.y;
    int q0 = blockIdx.x * 16;
    int tid  = threadIdx.x;
    int lane = tid & 63;
    int qg   = tid >> 6;                     // wave id: queries qg*4..+4
    int pg   = lane;                         // points pg*4..+4

    __shared__ float Qt[128][16];            // [c][q] 8 KB
    __shared__ float Pt[32][260];            // [c-chunk][p] 33.3 KB (pad 4)

    {
        int q = tid >> 4, c0 = (tid & 15) * 8;
        const float* src = stk_coor_bef + ((size_t)b * NBEF + q0 + q) * CCO + c0;
        float4 v0 = *reinterpret_cast<const float4*>(src);
        float4 v1 = *reinterpret_cast<const float4*>(src + 4);
        Qt[c0+0][q] = v0.x; Qt[c0+1][q] = v0.y; Qt[c0+2][q] = v0.z; Qt[c0+3][q] = v0.w;
        Qt[c0+4][q] = v1.x; Qt[c0+5][q] = v1.y; Qt[c0+6][q] = v1.z; Qt[c0+7][q] = v1.w;
    }

    float dot[4][4];
    #pragma unroll
    for (int a = 0; a < 4; ++a)
        #pragma unroll
        for (int c = 0; c < 4; ++c) dot[a][c] = 0.f;
    float qn[4] = {0.f, 0.f, 0.f, 0.f};
    float pn[4] = {0.f, 0.f, 0.f, 0.f};

    for (int ct = 0; ct < 4; ++ct) {
        __syncthreads();
        #pragma unroll
        for (int it = 0; it < 8; ++it) {
            int p  = (tid >> 3) + it * 32;
            int cl = (tid & 7) * 4;
            float4 v = *reinterpret_cast<const float4*>(
                stk_coor + ((size_t)b * NSTK + p) * CCO + ct * 32 + cl);
            Pt[cl+0][p] = v.x; Pt[cl+1][p] = v.y; Pt[cl+2][p] = v.z; Pt[cl+3][p] = v.w;
        }
        __syncthreads();
        #pragma unroll 8
        for (int c = 0; c < 32; ++c) {
            float4 qv = *reinterpret_cast<const float4*>(&Qt[ct*32 + c][qg*4]);
            float4 pv = *reinterpret_cast<const float4*>(&Pt[c][pg*4]);
            float qa[4] = {qv.x, qv.y, qv.z, qv.w};
            float pa[4] = {pv.x, pv.y, pv.z, pv.w};
            #pragma unroll
            for (int j = 0; j < 4; ++j) {
                qn[j] += qa[j] * qa[j];
                pn[j] += pa[j] * pa[j];
                #pragma unroll
                for (int k = 0; k < 4; ++k) dot[j][k] += qa[j] * pa[k];
            }
        }
    }

    #pragma unroll
    for (int qj = 0; qj < 4; ++qj) {
        unsigned long long kA = 0xFFFFFFFFFFFFFFFFull, kB = 0xFFFFFFFFFFFFFFFFull;
        #pragma unroll
        for (int pj = 0; pj < 4; ++pj) {
            float d2 = qn[qj] + pn[pj] - 2.f * dot[qj][pj];
            unsigned long long key =
                ((unsigned long long)f2ord(d2) << 32) | (unsigned int)(pg * 4 + pj);
            if (key < kA)      { kB = kA; kA = key; }
            else if (key < kB) { kB = key; }
        }
        unsigned long long m0 = wave_min_u64(kA);
        unsigned long long c2 = (kA == m0) ? kB : kA;
        unsigned long long m1 = wave_min_u64(c2);
        if (lane == 0) {
            float d0 = ord2f((unsigned int)(m0 >> 32));
            float d1 = ord2f((unsigned int)(m1 >> 32));
            int j0 = (int)(m0 & 0xffffffffu), j1 = (int)(m1 & 0xffffffffu);
            float r0 = 1.f / (d0 + 1e-8f);
            float r1 = 1.f / (d1 + 1e-8f);
            float s = r0 + r1;
            int q = q0 + qg * 4 + qj;
            idx_out[b * NBEF + q] = make_int2(j0, j1);
            w_out[b * NBEF + q]   = make_float2(r0 / s, r1 / s);
        }
    }
}

// ---------------- Kernel 1: merged one-time prep (A fragments + w_sp transpose) ----------------
__global__ __launch_bounds__(256) void prep_kernel(
    const float* __restrict__ w_ct,          // [128][128][4]
    const float* __restrict__ w_sp,          // [256][512]
    unsigned short* __restrict__ Aws,        // 65536 bf16
    float4* __restrict__ wTq,                // [128][256] (may be null)
    int do_wt)
{
    if (blockIdx.x < 32) {
        int g = blockIdx.x * 256 + threadIdx.x;  // 0..8191
        int lane = g & 63;
        int ks = (g >> 6) & 7;
        int mt16 = g >> 9;
        int m = mt16 * 16 + (lane & 15);
        int o = m & 127;
        int modd = (m >= 128);
        unsigned short t8[8];
        #pragma unroll
        for (int j = 0; j < 8; ++j) {
            int k = ks * 32 + (lane >> 4) * 8 + j;
            int i = k & 127;
            int tap = modd ? (k < 128 ? 2 : 0) : (k < 128 ? 3 : 1);
            t8[j] = f32_to_bf16(w_ct[((size_t)i * DNOUT + o) * 4 + tap]);
        }
        *reinterpret_cast<uint4*>(Aws + (size_t)g * 8) = *reinterpret_cast<const uint4*>(t8);
    } else if (do_wt) {
        int c4 = blockIdx.x - 32;                // 0..127
        int o  = threadIdx.x;                    // 0..255
        float4 v = *reinterpret_cast<const float4*>(w_sp + (size_t)o * SPIN + c4 * 4);
        wTq[c4 * 256 + o] = v;
    }
}

// ---------------- Kernel M: merged main — dense (blocks x<128) + sparse (x 128..159) ---------
// Dense path: R19 winner verbatim (barrier-free per-wave staging, ks-outer acc-resident MFMA,
// seam-free full-line epilogue).  Sparse path: R19 winner at 512 threads (2 groups x 8 n's).
// Co-scheduling lets sparse blocks fill dense's latency gaps (dense: 41% occupancy, no pipe
// saturated).  LDS = 71.8 KB union; sparse uses 33 KB of it.
__global__ __launch_bounds__(512, 4) void main_kernel(
    const float* __restrict__ DF,            // [16][128][256][32]
    const float* __restrict__ SF,            // [16][512][256]
    const unsigned short* __restrict__ Aws,  // fragment-linear A
    const float* __restrict__ w_sp,
    const float4* __restrict__ wTq,          // or null
    const float* __restrict__ b_ct,
    const float* __restrict__ gamma_dn,
    const float* __restrict__ beta_dn,
    const float* __restrict__ b_sp,
    const float* __restrict__ gamma_sp,
    const float* __restrict__ beta_sp,
    const int2* __restrict__ idxws, const float2* __restrict__ wgtws,
    float* __restrict__ out)                 // full output base
{
    __shared__ __align__(16) char smem[71808];
    int b   = blockIdx.y;
    int tid  = threadIdx.x;
    const float invs = 1.0f / sqrtf(1.0f + 1e-5f);

    if (blockIdx.x < 128) {
        // ================= DENSE path =================
        float* Y            = (float*)smem;                        // 32768 B
        unsigned short* Xs  = (unsigned short*)(smem + 32768);     // 37376 B
        float* bnb          = (float*)(smem + 70144);
        float* bns          = (float*)(smem + 70656);
        float* bnt          = (float*)(smem + 71168);
        int2*  sij          = (int2*)(smem + 71680);
        float2* swt         = (float2*)(smem + 71728);
        float* outd = out + SP_ELEMS;

        int blk = blockIdx.x;
        int n0  = blk * 4;
        int S0  = n0 * 32;
        int T0  = n0 * 64;
        int lane = tid & 63;
        int wid  = tid >> 6;
        int rit  = lane & 15;
        int kgrp = lane >> 4;

        if (tid < 128) {
            bnb[tid] = b_ct[tid];
            bns[tid] = gamma_dn[tid] * invs;
            bnt[tid] = beta_dn[tid];
        }
        if (tid < 6) {
            int s = n0 - 1 + tid;
            s = (s < 0) ? 0 : ((s > NBEF - 1) ? NBEF - 1 : s);
            sij[tid] = idxws[b * NBEF + s];
            swt[tid] = wgtws[b * NBEF + s];
        }
        if (tid < 256) {
            uint4 z = make_uint4(0, 0, 0, 0);
            *reinterpret_cast<uint4*>(&Xs[130 * 128 + tid * 8]) = z;
        }
        __syncthreads();                     // barrier 1

        const float* DFb = DF + (size_t)b * (DNIN * NSTK * NPNT);

        if (tid < 256) {                     // halo cols 0 and 129
            int i    = tid & 127;
            int side = tid >> 7;
            int col  = side ? 129 : 0;
            int L    = side ? (S0 + 128) : (S0 - 1);
            L = (L < 0) ? 0 : ((L > 16383) ? 16383 : L);
            int stroke = L >> 5, pt = L & 31;
            int slot = stroke - (n0 - 1);
            int2  ij = sij[slot];
            float2 w = swt[slot];
            float v = w.x * DFb[(size_t)i * 8192 + (size_t)ij.x * NPNT + pt]
                    + w.y * DFb[(size_t)i * 8192 + (size_t)ij.y * NPNT + pt];
            int dst = col * 128 + ((((i >> 3) ^ (col & 15))) << 3) + (i & 7);
            Xs[dst] = f32_to_bf16(v);
        }

        // barrier-free per-wave staging
        float* Ysl = &Y[wid * 1024];
        int swq = (lane & 7) ^ ((lane >> 3) & 7);
        int sp2 = lane & 31;
        int so  = lane >> 5;
        int goct = wid * 2 + so;
        #pragma unroll 1
        for (int nl = 0; nl < 4; ++nl) {
            int2 ij = sij[nl + 1];
            #pragma unroll
            for (int p = 0; p < 2; ++p) {
                int jj = p ? ij.y : ij.x;
                #pragma unroll
                for (int q = 0; q < 2; ++q) {
                    int i = 16 * wid + q * 8 + (lane >> 3);
                    const float* g = DFb + (size_t)i * 8192 + (size_t)jj * NPNT + (swq << 2);
                    __builtin_amdgcn_global_load_lds((gas1_t)(const void*)g,
                        (las3_t)(void*)&Ysl[p * 512 + q * 256], 16, 0, 0);
                }
            }
            asm volatile("s_waitcnt vmcnt(0)" ::: "memory");
            __builtin_amdgcn_sched_barrier(0);
            {
                float2 w = swt[nl + 1];
                unsigned short t8[8];
                #pragma unroll
                for (int pp = 0; pp < 8; ++pp) {
                    int a = (so * 8 + pp) * 32 + (((sp2 >> 2) ^ pp) << 2) + (sp2 & 3);
                    float v = w.x * Ysl[a] + w.y * Ysl[512 + a];
                    t8[pp] = f32_to_bf16(v);
                }
                int col = nl * 32 + sp2 + 1;
                int dst = col * 128 + ((goct ^ (col & 15)) << 3);
                *reinterpret_cast<uint4*>(&Xs[dst]) = *reinterpret_cast<const uint4*>(t8);
            }
        }
        __syncthreads();                     // barrier 2: Xs ready

        // MFMA: ks-outer / nt-inner, acc[9][2] resident
        f32x4v acc[9][2];
        #pragma unroll
        for (int nt = 0; nt < 9; ++nt) {
            acc[nt][0] = (f32x4v){0.f, 0.f, 0.f, 0.f};
            acc[nt][1] = (f32x4v){0.f, 0.f, 0.f, 0.f};
        }
        #pragma unroll
        for (int kh = 0; kh < 2; ++kh) {
            bf16x8v af[2][4];
            #pragma unroll
            for (int mt = 0; mt < 2; ++mt) {
                int mt16 = wid + mt * 8;
                #pragma unroll
                for (int k4 = 0; k4 < 4; ++k4) {
                    int ks = kh * 4 + k4;
                    af[mt][k4] = *reinterpret_cast<const bf16x8v*>(
                        Aws + (((size_t)(mt16 * 8 + ks)) * 64 + lane) * 8);
                }
            }
            #pragma unroll
            for (int k4 = 0; k4 < 4; ++k4) {
                int ks   = kh * 4 + k4;
                int kb   = ks * 32 + kgrp * 8;
                int half = kb >> 7;
                int i    = kb & 127;
                #pragma unroll
                for (int nt = 0; nt < 9; ++nt) {
                    int col = nt * 16 + rit + half;
                    int src = col * 128 + ((((i >> 3) ^ (col & 15))) << 3);
                    bf16x8v bfrag = *reinterpret_cast<const bf16x8v*>(&Xs[src]);
                    acc[nt][0] = __builtin_amdgcn_mfma_f32_16x16x32_bf16(af[0][k4], bfrag, acc[nt][0], 0, 0, 0);
                    acc[nt][1] = __builtin_amdgcn_mfma_f32_16x16x32_bf16(af[1][k4], bfrag, acc[nt][1], 0, 0, 0);
                }
            }
        }

        // seam-free epilogue
        int srcl = (lane & 48) | ((lane + 1) & 15);
        #pragma unroll
        for (int nt = 0; nt < 8; ++nt) {
            int c = nt * 16 + rit;
            #pragma unroll
            for (int q = 0; q < 4; ++q) {
                float srcv = (rit == 0) ? acc[nt + 1][1][q] : acc[nt][1][q];
                float a1n = __shfl(srcv, srcl, 64);
                int o = wid * 16 + kgrp * 4 + q;
                float bias = bnb[o], scale = bns[o], beta = bnt[o];
                float ye = fast_gelu((acc[nt][0][q] + bias) * scale + beta);
                float yo = fast_gelu((a1n + bias) * scale + beta);
                size_t rowbase = (((size_t)b * DNOUT + o) << 15) + (size_t)T0;
                *reinterpret_cast<float2*>(outd + rowbase + 2 * c) = make_float2(ye, yo);
            }
        }
    } else {
        // ================= SPARSE path (2 groups x 8 n's) =================
        float*  fsb  = (float*)smem;                      // fs[2][512][8] = 32768 B
        int2*   ssij = (int2*)(smem + 32768);             // [16]
        float2* sswt = (float2*)(smem + 32896);           // [16]

        int sx = blockIdx.x - 128;                        // 0..31
        int tid256 = tid & 255;
        int group  = tid >> 8;                            // 0/1
        int n0 = sx * 16 + group * 8;

        if (tid < 16) {
            ssij[tid] = idxws[b * NBEF + sx * 16 + tid];
            sswt[tid] = wgtws[b * NBEF + sx * 16 + tid];
        }
        __syncthreads();

        float* fsg = fsb + group * 4096;
        for (int l = tid256; l < SPIN * 8; l += 256) {
            int c = l >> 3, nn = l & 7;
            int2  ij = ssij[group * 8 + nn];
            float2 w = sswt[group * 8 + nn];
            const float* row = SF + ((size_t)b * SPIN + c) * NSTK;
            fsg[l] = w.x * row[ij.x] + w.y * row[ij.y];
        }
        __syncthreads();

        int o = tid256;
        float acc[8] = {0,0,0,0,0,0,0,0};
        #pragma unroll 2
        for (int c4 = 0; c4 < SPIN / 4; ++c4) {
            float4 a = wTq ? wTq[c4 * 256 + o]
                           : *reinterpret_cast<const float4*>(w_sp + (size_t)o * SPIN + c4 * 4);
            int c = c4 * 4;
            float4 fA[4], fB[4];
            #pragma unroll
            for (int k = 0; k < 4; ++k) {
                fA[k] = *reinterpret_cast<const float4*>(&fsg[(c + k) * 8]);
                fB[k] = *reinterpret_cast<const float4*>(&fsg[(c + k) * 8 + 4]);
            }
            const float* a4 = reinterpret_cast<const float*>(&a);
            #pragma unroll
            for (int nn = 0; nn < 4; ++nn) {
                float sA = 0.f, sB = 0.f;
                #pragma unroll
                for (int k = 0; k < 4; ++k) {
                    sA += a4[k] * reinterpret_cast<const float*>(&fA[k])[nn];
                    sB += a4[k] * reinterpret_cast<const float*>(&fB[k])[nn];
                }
                acc[nn]     += sA;
                acc[nn + 4] += sB;
            }
        }

        float bias  = b_sp[o];
        float scale = gamma_sp[o] * invs;
        float beta  = beta_sp[o];
        float r[8];
        #pragma unroll
        for (int q = 0; q < 8; ++q)
            r[q] = fast_gelu((acc[q] + bias) * scale + beta);
        float* dst = out + ((size_t)b * SPOUT + o) * NBEF + n0;
        *reinterpret_cast<float4*>(dst)     = make_float4(r[0], r[1], r[2], r[3]);
        *reinterpret_cast<float4*>(dst + 4) = make_float4(r[4], r[5], r[6], r[7]);
    }
}

extern "C" void kernel_launch(void* const* d_in, const int* in_sizes, int n_in,
                              void* d_out, int out_size, void* d_ws, size_t ws_size,
                              hipStream_t stream) {
    const float* sparse_fea   = (const float*)d_in[0];
    const float* dense_fea    = (const float*)d_in[1];
    const float* stk_coor     = (const float*)d_in[2];
    const float* stk_coor_bef = (const float*)d_in[3];
    const float* w_sp     = (const float*)d_in[4];
    const float* b_sp     = (const float*)d_in[5];
    const float* gamma_sp = (const float*)d_in[6];
    const float* beta_sp  = (const float*)d_in[7];
    const float* w_ct     = (const float*)d_in[8];
    const float* b_ct     = (const float*)d_in[9];
    const float* gamma_dn = (const float*)d_in[10];
    const float* beta_dn  = (const float*)d_in[11];
    float* out = (float*)d_out;

    char* ws = (char*)d_ws;
    int2*   idx = (int2*)ws;                               // 64 KB
    float2* wgt = (float2*)(ws + 65536);                   // 64 KB
    unsigned short* Aws = (unsigned short*)(ws + 131072);  // 128 KB
    bool use_wt = (ws_size >= 786432);                     // + 512 KB wTq = 768 KB total
    float4* wTq = use_wt ? (float4*)(ws + 262144) : nullptr;

    knn_kernel<<<dim3(NBEF / 16, NB), 256, 0, stream>>>(stk_coor, stk_coor_bef, idx, wgt);
    prep_kernel<<<use_wt ? 160 : 32, 256, 0, stream>>>(w_ct, w_sp, Aws, wTq, use_wt ? 1 : 0);
    main_kernel<<<dim3(160, NB), 512, 0, stream>>>(
        dense_fea, sparse_fea, Aws, w_sp, wTq,
        b_ct, gamma_dn, beta_dn, b_sp, gamma_sp, beta_sp,
        idx, wgt, out);
}